// Round 1
// baseline (226.359 us; speedup 1.0000x reference)
//
#include <hip/hip_runtime.h>

#define EPB 32          // envs per block
#define TPE 8           // threads per env
#define BLOCK 256
#define HS 292          // H LDS stride (24*12=288 + 4 pad; 292%32=4 -> bank-distinct envs)
#define GS 148          // Ginv LDS stride (144 + 4 pad; 148%32=20 -> bank-distinct)
#define SS 28           // s / aux stride (24 + 4 pad; 112B = 16B aligned, bank-distinct)

// Gauss-Jordan on a 12-row system distributed: thread t owns row t (r0) and,
// if t<4, row t+8 (r1). Width W columns. Pivot row broadcast via LDS (piv).
// SPD input -> no pivoting needed.
template<int W>
__device__ __forceinline__ void gauss_jordan(float* r0, float* r1, float* piv, int t) {
#pragma unroll
  for (int k = 0; k < 12; ++k) {
    if (k < 8) {
      if (t == k) {
        float inv = 1.0f / r0[k];
#pragma unroll
        for (int c = 0; c < W; ++c) { r0[c] *= inv; piv[c] = r0[c]; }
      }
    } else {
      if (t == k - 8) {
        float inv = 1.0f / r1[k];
#pragma unroll
        for (int c = 0; c < W; ++c) { r1[c] *= inv; piv[c] = r1[c]; }
      }
    }
    __syncthreads();
    float m0 = (t == k) ? 0.0f : r0[k];
#pragma unroll
    for (int c = 0; c < W; ++c) r0[c] = fmaf(-m0, piv[c], r0[c]);
    float m1 = ((t + 8) == k) ? 0.0f : r1[k];
#pragma unroll
    for (int c = 0; c < W; ++c) r1[c] = fmaf(-m1, piv[c], r1[c]);
    __syncthreads();
  }
}

__global__ __launch_bounds__(BLOCK, 2)
void pdhg_kernel(const float* __restrict__ P, const float* __restrict__ q,
                 const float* __restrict__ H, const float* __restrict__ b,
                 const float* __restrict__ cf, const int* __restrict__ itp,
                 float* __restrict__ out, int Btot) {
  __shared__ __align__(16) float sH[EPB * HS];
  __shared__ __align__(16) float sGi[EPB * GS];   // P, then Ginv
  __shared__ __align__(16) float sS[2 * EPB * SS];
  __shared__ __align__(16) float sAux[EPB * SS];

  const int tid = threadIdx.x;
  const int e   = tid >> 3;
  const int t   = tid & 7;
  const int env = blockIdx.x * EPB + e;
  const int niter = itp[0];
  const int r0w = 3 * t;   // this thread owns 24-space rows r0w..r0w+2

  // ---- cooperative, coalesced staging of H and P into LDS ----
  {
    const float* gH = H + (size_t)blockIdx.x * EPB * 288;
    for (int i = tid; i < EPB * 288; i += BLOCK) {
      int ee = i / 288, off = i - ee * 288;
      sH[ee * HS + off] = gH[i];
    }
    const float* gP = P + (size_t)blockIdx.x * EPB * 144;
    for (int i = tid; i < EPB * 144; i += BLOCK) {
      int ee = i / 144, off = i - ee * 144;
      sGi[ee * GS + off] = gP[i];
    }
  }
  __syncthreads();

  const float* myH = &sH[e * HS];
  float* piv = &sAux[e * SS];

  // ---- build aug rows [G|I] (G = P + HtH) and [P|q], register-resident ----
  float g0[24], g1[24], p0[13], p1[13];
  {
    float hr[24];
#pragma unroll
    for (int k = 0; k < 24; ++k) hr[k] = myH[k * 12 + t];
#pragma unroll
    for (int c = 0; c < 12; ++c) {
      float acc = sGi[e * GS + t * 12 + c];
#pragma unroll
      for (int k = 0; k < 24; ++k) acc = fmaf(hr[k], myH[k * 12 + c], acc);
      g0[c] = acc;
    }
#pragma unroll
    for (int c = 0; c < 12; ++c) g0[12 + c] = (c == t) ? 1.0f : 0.0f;
#pragma unroll
    for (int c = 0; c < 12; ++c) p0[c] = sGi[e * GS + t * 12 + c];
    p0[12] = q[(size_t)env * 12 + t];

    if (t < 4) {
      float hr2[24];
#pragma unroll
      for (int k = 0; k < 24; ++k) hr2[k] = myH[k * 12 + t + 8];
#pragma unroll
      for (int c = 0; c < 12; ++c) {
        float acc = sGi[e * GS + (t + 8) * 12 + c];
#pragma unroll
        for (int k = 0; k < 24; ++k) acc = fmaf(hr2[k], myH[k * 12 + c], acc);
        g1[c] = acc;
      }
#pragma unroll
      for (int c = 0; c < 12; ++c) g1[12 + c] = (c == t + 8) ? 1.0f : 0.0f;
#pragma unroll
      for (int c = 0; c < 12; ++c) p1[c] = sGi[e * GS + (t + 8) * 12 + c];
      p1[12] = q[(size_t)env * 12 + t + 8];
    } else {
#pragma unroll
      for (int c = 0; c < 24; ++c) g1[c] = 0.0f;
#pragma unroll
      for (int c = 0; c < 13; ++c) p1[c] = 0.0f;
    }
  }
  __syncthreads();

  // ---- invert G = P + HtH ----
  gauss_jordan<24>(g0, g1, piv, t);

  // write Ginv over P in LDS (P reads all completed: GJ's barriers precede)
#pragma unroll
  for (int c = 0; c < 12; ++c) sGi[e * GS + t * 12 + c] = g0[12 + c];
  if (t < 4) {
#pragma unroll
    for (int c = 0; c < 12; ++c) sGi[e * GS + (t + 8) * 12 + c] = g1[12 + c];
  }

  // ---- solve P tsol = q ----
  gauss_jordan<13>(p0, p1, piv, t);
  sAux[e * SS + t] = p0[12];
  if (t < 4) sAux[e * SS + t + 8] = p1[12];
  __syncthreads();
  float tsol[12];
#pragma unroll
  for (int c = 0; c < 12; ++c) tsol[c] = sAux[e * SS + c];

  // ---- Fm rows (register resident), v = H*tsol - b ----
  float bown[3], cfr[3];
#pragma unroll
  for (int i = 0; i < 3; ++i) {
    bown[i] = b[(size_t)env * 24 + r0w + i];
    cfr[i]  = cf[(size_t)env * 24 + r0w + i];
  }
  float Fm[3][24];
  float vown[3];
  {
    float hrow[3][12];
#pragma unroll
    for (int i = 0; i < 3; ++i)
#pragma unroll
      for (int c = 0; c < 12; ++c) hrow[i][c] = myH[(r0w + i) * 12 + c];

    float hg[3][12];
#pragma unroll
    for (int j = 0; j < 12; ++j) {
      float a0 = 0.f, a1 = 0.f, a2 = 0.f;
#pragma unroll
      for (int c = 0; c < 12; ++c) {
        float gv = sGi[e * GS + c * 12 + j];
        a0 = fmaf(hrow[0][c], gv, a0);
        a1 = fmaf(hrow[1][c], gv, a1);
        a2 = fmaf(hrow[2][c], gv, a2);
      }
      hg[0][j] = a0; hg[1][j] = a1; hg[2][j] = a2;
    }
#pragma unroll
    for (int j = 0; j < 24; ++j) {
      float a0 = 0.f, a1 = 0.f, a2 = 0.f;
#pragma unroll
      for (int c = 0; c < 12; ++c) {
        float hv = myH[j * 12 + c];
        a0 = fmaf(hg[0][c], hv, a0);
        a1 = fmaf(hg[1][c], hv, a1);
        a2 = fmaf(hg[2][c], hv, a2);
      }
      Fm[0][j] = ((j == r0w)     ? 1.f : 0.f) - a0;
      Fm[1][j] = ((j == r0w + 1) ? 1.f : 0.f) - a1;
      Fm[2][j] = ((j == r0w + 2) ? 1.f : 0.f) - a2;
    }
#pragma unroll
    for (int i = 0; i < 3; ++i) {
      float acc = 0.f;
#pragma unroll
      for (int c = 0; c < 12; ++c) acc = fmaf(hrow[i][c], tsol[c], acc);
      vown[i] = acc - bown[i];
    }
  }
  __syncthreads();                 // tsol reads done before overwriting sAux
#pragma unroll
  for (int i = 0; i < 3; ++i) sAux[e * SS + r0w + i] = vown[i];
  __syncthreads();
  float mu[3];
#pragma unroll
  for (int i = 0; i < 3; ++i) {
    float acc = 0.f;
#pragma unroll
    for (int j = 0; j < 24; ++j) acc = fmaf(Fm[i][j], sAux[e * SS + j], acc);
    mu[i] = acc;
  }

  // ---- iterations: s = l+z; w = Fm s + mu; l = w; z = project(s - 2w)*cf ----
  float l[3] = {0.f, 0.f, 0.f}, z[3] = {0.f, 0.f, 0.f};
  int buf = 0;
  for (int it = 0; it < niter; ++it) {
    float so[3];
    float* sw = &sS[buf * (EPB * SS) + e * SS + r0w];
#pragma unroll
    for (int i = 0; i < 3; ++i) { so[i] = l[i] + z[i]; sw[i] = so[i]; }
    __syncthreads();               // one barrier/iter (double-buffered s)
    const float* sv = &sS[buf * (EPB * SS) + e * SS];
    float sval[24];
#pragma unroll
    for (int j = 0; j < 24; ++j) sval[j] = sv[j];   // 6x ds_read_b128, broadcast
    float w[3];
#pragma unroll
    for (int i = 0; i < 3; ++i) {
      float acc = mu[i];
#pragma unroll
      for (int j = 0; j < 24; ++j) acc = fmaf(Fm[i][j], sval[j], acc);
      w[i] = acc;
    }
#pragma unroll
    for (int i = 0; i < 3; ++i) {
      l[i] = w[i];
      z[i] = fmaf(-2.0f, w[i], so[i]);   // z_pre
    }
    if (t < 4) {                         // SOC cone t: zero block unless z[2] > 0
      float m = (z[2] > 0.0f) ? 1.0f : 0.0f;
#pragma unroll
      for (int i = 0; i < 3; ++i) z[i] = z[i] * m * cfr[i];
    } else {                             // box rows 12..23
#pragma unroll
      for (int i = 0; i < 3; ++i) z[i] = fminf(fmaxf(z[i], -10.0f), 10.0f) * cfr[i];
    }
    buf ^= 1;
  }

  // ---- outputs: lz, then x = (HtH)^-1 Ht (z - b) ----
  float* xout  = out;
  float* lzout = out + (size_t)Btot * 12;
#pragma unroll
  for (int i = 0; i < 3; ++i) {
    lzout[(size_t)env * 48 + r0w + i]      = l[i];
    lzout[(size_t)env * 48 + 24 + r0w + i] = z[i];
  }
  __syncthreads();                 // covers niter==0 path before sAux reuse
#pragma unroll
  for (int i = 0; i < 3; ++i) sAux[e * SS + r0w + i] = z[i] - bown[i];
  __syncthreads();

  float h0[13], h1[13];
  {
    float hr[24];
#pragma unroll
    for (int k = 0; k < 24; ++k) hr[k] = myH[k * 12 + t];
#pragma unroll
    for (int c = 0; c < 12; ++c) {
      float acc = 0.f;
#pragma unroll
      for (int k = 0; k < 24; ++k) acc = fmaf(hr[k], myH[k * 12 + c], acc);
      h0[c] = acc;
    }
    float accu = 0.f;
#pragma unroll
    for (int k = 0; k < 24; ++k) accu = fmaf(hr[k], sAux[e * SS + k], accu);
    h0[12] = accu;
    if (t < 4) {
      float hr2[24];
#pragma unroll
      for (int k = 0; k < 24; ++k) hr2[k] = myH[k * 12 + t + 8];
#pragma unroll
      for (int c = 0; c < 12; ++c) {
        float a2 = 0.f;
#pragma unroll
        for (int k = 0; k < 24; ++k) a2 = fmaf(hr2[k], myH[k * 12 + c], a2);
        h1[c] = a2;
      }
      float a3 = 0.f;
#pragma unroll
      for (int k = 0; k < 24; ++k) a3 = fmaf(hr2[k], sAux[e * SS + k], a3);
      h1[12] = a3;
    } else {
#pragma unroll
      for (int c = 0; c < 13; ++c) h1[c] = 0.f;
    }
  }
  __syncthreads();                 // rv reads done before GJ reuses sAux
  gauss_jordan<13>(h0, h1, piv, t);
  xout[(size_t)env * 12 + t] = h0[12];
  if (t < 4) xout[(size_t)env * 12 + t + 8] = h1[12];
}

extern "C" void kernel_launch(void* const* d_in, const int* in_sizes, int n_in,
                              void* d_out, int out_size, void* d_ws, size_t ws_size,
                              hipStream_t stream) {
  const float* P  = (const float*)d_in[0];
  const float* q  = (const float*)d_in[1];
  const float* H  = (const float*)d_in[2];
  const float* b  = (const float*)d_in[3];
  const float* cf = (const float*)d_in[4];
  const int*   it = (const int*)d_in[5];
  float* out = (float*)d_out;
  const int B = in_sizes[1] / 12;       // q is [B,12]
  const int grid = B / EPB;             // 16384/32 = 512 blocks, 2 blocks/CU
  pdhg_kernel<<<grid, BLOCK, 0, stream>>>(P, q, H, b, cf, it, out, B);
}